// Round 4
// baseline (90.604 us; speedup 1.0000x reference)
//
#include <hip/hip_runtime.h>

#define N 8192
#define DIM 64
#define KS 256      // f32 per row per subtile
#define NSUB 32     // 8192 / KS
#define NBUF 4      // LDS buffers (stage-ahead = 3)

typedef float f32x4 __attribute__((ext_vector_type(4)));
typedef short bf16x8 __attribute__((ext_vector_type(8)));
typedef unsigned short u16;

__device__ __forceinline__ u16 f32_to_bf16_rne(float f) {
  unsigned int u = __float_as_uint(f);
  return (u16)((u + 0x7FFFu + ((u >> 16) & 1u)) >> 16);
}

// x (f32 [N][64]) -> xbT (bf16 [64][N]).  128 blocks x 256 thr.
// Reads coalesced (256B per wave-inst); writes 2x16B per thread.
__global__ void cvtT_kernel(const float* __restrict__ x, u16* __restrict__ xbT) {
  int t = threadIdx.x;
  int i0 = blockIdx.x * 64;
  int d = t & 63;
  int r = t >> 6;               // wave id = i-quarter
  int ib = i0 + r * 16;
  alignas(16) u16 v[16];
#pragma unroll
  for (int m = 0; m < 16; ++m)
    v[m] = f32_to_bf16_rne(x[(size_t)(ib + m) * DIM + d]);
  *reinterpret_cast<bf16x8*>(xbT + (size_t)d * N + ib) = *reinterpret_cast<bf16x8*>(&v[0]);
  *reinterpret_cast<bf16x8*>(xbT + (size_t)d * N + ib + 8) = *reinterpret_cast<bf16x8*>(&v[8]);
}

// Ax = A @ x.  512 blocks (16 rows each) x 256 thr (4 waves), full K per block.
// A staged f32 via global_load_lds (1KB contiguous per inst), 4-buffer pipeline,
// counted vmcnt (never 0 in steady state), raw barriers.  Waves split K
// (wave w -> ksteps 2w,2w+1 of each subtile); partials reduced via LDS.
__global__ __launch_bounds__(256, 2) void ax_kernel(const float* __restrict__ A,
                                                    const u16* __restrict__ xbT,
                                                    float* __restrict__ Ax) {
  __shared__ float At[NBUF][16][KS];   // 64 KiB
  int i0 = blockIdx.x * 16;
  int tid = threadIdx.x;
  int w = tid >> 6, lane = tid & 63;
  int c = lane & 15, q = lane >> 4;

  f32x4 acc[4];
#pragma unroll
  for (int nt = 0; nt < 4; ++nt) acc[nt] = (f32x4){0.f, 0.f, 0.f, 0.f};

  // stage(s): wave w DMA-loads rows w*4..w*4+3, cols [s*KS, s*KS+KS)
#define STAGE(s_)                                                                   \
  {                                                                                 \
    int buf_ = (s_) & (NBUF - 1);                                                   \
    _Pragma("unroll") for (int rr = 0; rr < 4; ++rr) {                              \
      int row_ = w * 4 + rr;                                                        \
      const float* gp_ = A + (size_t)(i0 + row_) * N + (s_)*KS + lane * 4;          \
      __builtin_amdgcn_global_load_lds(                                             \
          (const __attribute__((address_space(1))) unsigned int*)gp_,               \
          (__attribute__((address_space(3))) unsigned int*)&At[buf_][row_][0],      \
          16, 0, 0);                                                                \
    }                                                                               \
  }

  STAGE(0); STAGE(1); STAGE(2);   // 12 loads outstanding per wave

  for (int s = 0; s < NSUB; ++s) {
    if (s < NSUB - 3) {
      STAGE(s + 3);
      asm volatile("s_waitcnt vmcnt(12)" ::: "memory");
    } else if (s == NSUB - 3) {
      asm volatile("s_waitcnt vmcnt(8)" ::: "memory");
    } else if (s == NSUB - 2) {
      asm volatile("s_waitcnt vmcnt(4)" ::: "memory");
    } else {
      asm volatile("s_waitcnt vmcnt(0)" ::: "memory");
    }
    __builtin_amdgcn_sched_barrier(0);
    __builtin_amdgcn_s_barrier();
    __builtin_amdgcn_sched_barrier(0);

    int buf = s & (NBUF - 1);
#pragma unroll
    for (int t2 = 0; t2 < 2; ++t2) {
      int kk = w * 2 + t2;  // this wave's kstep within the subtile
      const float* ap = &At[buf][c][kk * 32 + q * 8];
      f32x4 alo = *reinterpret_cast<const f32x4*>(ap);
      f32x4 ahi = *reinterpret_cast<const f32x4*>(ap + 4);
      bf16x8 afv;
      afv[0] = (short)f32_to_bf16_rne(alo[0]);
      afv[1] = (short)f32_to_bf16_rne(alo[1]);
      afv[2] = (short)f32_to_bf16_rne(alo[2]);
      afv[3] = (short)f32_to_bf16_rne(alo[3]);
      afv[4] = (short)f32_to_bf16_rne(ahi[0]);
      afv[5] = (short)f32_to_bf16_rne(ahi[1]);
      afv[6] = (short)f32_to_bf16_rne(ahi[2]);
      afv[7] = (short)f32_to_bf16_rne(ahi[3]);
      const u16* bp = xbT + (size_t)s * KS + kk * 32 + q * 8;
#pragma unroll
      for (int nt = 0; nt < 4; ++nt) {
        bf16x8 bfv = *reinterpret_cast<const bf16x8*>(bp + (size_t)(nt * 16 + c) * N);
        acc[nt] = __builtin_amdgcn_mfma_f32_16x16x32_bf16(afv, bfv, acc[nt], 0, 0, 0);
      }
    }
    __builtin_amdgcn_s_barrier();
    __builtin_amdgcn_sched_barrier(0);
  }
#undef STAGE

  // Epilogue: reduce 4 waves' K-partials.  acc[nt][v] = partial Ax[i0+q*4+v][nt*16+c].
  float* Red = &At[0][0][0];  // reuse: [4 waves][16 i][64 d] f32 = 16 KiB
#pragma unroll
  for (int nt = 0; nt < 4; ++nt)
#pragma unroll
    for (int v = 0; v < 4; ++v)
      Red[(w * 16 + q * 4 + v) * 64 + nt * 16 + c] = acc[nt][v];
  __syncthreads();
  int ii = tid >> 4, dq = tid & 15;
  f32x4 sum = *reinterpret_cast<f32x4*>(&Red[(0 * 16 + ii) * 64 + dq * 4]);
#pragma unroll
  for (int ww = 1; ww < 4; ++ww) {
    f32x4 p = *reinterpret_cast<f32x4*>(&Red[(ww * 16 + ii) * 64 + dq * 4]);
    sum += p;
  }
  *reinterpret_cast<f32x4*>(&Ax[(size_t)(i0 + ii) * 64 + dq * 4]) = sum;
}

// out[i][d] = 1 - 0.1*x[i][d] - 0.01*<x_i, Ax_i>.  512 blocks x 256 thr (16 rows/block).
__global__ void finish_kernel(const float* __restrict__ x,
                              const float* __restrict__ Ax,
                              float* __restrict__ out) {
  int tid = threadIdx.x;
  int i = blockIdx.x * 16 + (tid >> 4);
  int dq = tid & 15;
  size_t base = (size_t)i * DIM + dq * 4;
  f32x4 xv = *reinterpret_cast<const f32x4*>(x + base);
  f32x4 av = *reinterpret_cast<const f32x4*>(Ax + base);
  float p = xv[0] * av[0] + xv[1] * av[1] + xv[2] * av[2] + xv[3] * av[3];
  p += __shfl_xor(p, 1);
  p += __shfl_xor(p, 2);
  p += __shfl_xor(p, 4);
  p += __shfl_xor(p, 8);
  f32x4 o;
  o[0] = 1.0f - 0.1f * xv[0] - 0.01f * p;
  o[1] = 1.0f - 0.1f * xv[1] - 0.01f * p;
  o[2] = 1.0f - 0.1f * xv[2] - 0.01f * p;
  o[3] = 1.0f - 0.1f * xv[3] - 0.01f * p;
  *reinterpret_cast<f32x4*>(out + base) = o;
}

extern "C" void kernel_launch(void* const* d_in, const int* in_sizes, int n_in,
                              void* d_out, int out_size, void* d_ws, size_t ws_size,
                              hipStream_t stream) {
  // d_in[0] = t (unused), d_in[1] = x f32 [8192][64], d_in[2] = A f32 [8192][8192]
  const float* x = (const float*)d_in[1];
  const float* A = (const float*)d_in[2];
  float* out = (float*)d_out;

  u16* xbT = (u16*)d_ws;                                        // 1 MiB bf16 x^T
  float* Ax = (float*)((char*)d_ws + (size_t)2 * 1024 * 1024);  // 2 MiB

  cvtT_kernel<<<128, 256, 0, stream>>>(x, xbT);
  ax_kernel<<<512, 256, 0, stream>>>(A, xbT, Ax);
  finish_kernel<<<512, 256, 0, stream>>>(x, Ax, out);
}